// Round 16
// baseline (305.818 us; speedup 1.0000x reference)
//
#include <hip/hip_runtime.h>

typedef unsigned short ushort_t;
typedef unsigned int uint_t;
typedef __attribute__((ext_vector_type(8))) short short8;
typedef __attribute__((ext_vector_type(4))) float floatx4;
typedef __attribute__((ext_vector_type(4))) unsigned short ushortx4;

// ---------- bf16 helpers ----------
__device__ __forceinline__ ushort_t f2bf(float f){
  uint_t u = __builtin_bit_cast(uint_t, f);
  u += 0x7FFFu + ((u >> 16) & 1u);          // RNE
  return (ushort_t)(u >> 16);
}
__device__ __forceinline__ float bf2f(ushort_t u){
  uint_t x = ((uint_t)u) << 16;
  return __builtin_bit_cast(float, x);
}
__device__ __forceinline__ uint_t packbf2(float a, float b){
  return (uint_t)f2bf(a) | ((uint_t)f2bf(b) << 16);
}

// ---------- global -> LDS direct DMA (16B per lane, dest = base + lane*16) ----------
__device__ __forceinline__ void gload16(const void* g, void* l){
  __builtin_amdgcn_global_load_lds(
      (const __attribute__((address_space(1))) void*)g,
      (__attribute__((address_space(3))) void*)l, 16, 0, 0);
}

// barrier that is ALSO a compiler memory fence (raw s_barrier builtin is NOT:
// LLVM may move LDS/global_load_lds ops across it -> replay-dependent races).
#define FENCED_BARRIER() asm volatile("s_barrier" ::: "memory")

// ---------- weight fp32 -> bf16 pre-convert ----------
// dst (ushort elems): w_in(196608) | w_val(65536) | w_out(65536) | w_oc(65536)
//                   | w1(262144) | w2(262144) | w_off(65536) | w_attw(32768)
__global__ __launch_bounds__(256) void convert_w_kernel(const float* __restrict__ w_in,
    const float* __restrict__ w_val, const float* __restrict__ w_out,
    const float* __restrict__ w_oc, const float* __restrict__ w1,
    const float* __restrict__ w2, const float* __restrict__ w_off,
    const float* __restrict__ w_attw, ushort_t* __restrict__ dst){
  int j = (blockIdx.x*256 + threadIdx.x) * 4;
  if (j >= 1015808) return;
  const float* src; int off;
  if      (j < 196608){ src = w_in;   off = 0;      }
  else if (j < 262144){ src = w_val;  off = 196608; }
  else if (j < 327680){ src = w_out;  off = 262144; }
  else if (j < 393216){ src = w_oc;   off = 327680; }
  else if (j < 655360){ src = w1;     off = 393216; }
  else if (j < 917504){ src = w2;     off = 655360; }
  else if (j < 983040){ src = w_off;  off = 917504; }
  else                { src = w_attw; off = 983040; }
  float4 v = *(const float4*)(src + (j - off));
  uint2 u; u.x = packbf2(v.x, v.y); u.y = packbf2(v.z, v.w);
  *(uint2*)(dst + j) = u;
}

// ---------- pack b_off | b_attw into one fp32 vector (384) ----------
__global__ __launch_bounds__(256) void pack_bias_kernel(const float* __restrict__ b_off,
    const float* __restrict__ b_attw, float* __restrict__ dst){
  int t = threadIdx.x;
  dst[t] = b_off[t];
  if (t < 128) dst[256 + t] = b_attw[t];
}

// ---------- elementwise add (float4) ----------
__global__ __launch_bounds__(256) void add_kernel(const float* __restrict__ a,
    const float* __restrict__ b, float* __restrict__ c, int n4){
  int i = blockIdx.x * 256 + threadIdx.x;
  if (i < n4){
    float4 x = ((const float4*)a)[i];
    float4 y = ((const float4*)b)[i];
    float4 z; z.x=x.x+y.x; z.y=x.y+y.y; z.z=x.z+y.z; z.w=x.w+y.w;
    ((float4*)c)[i] = z;
  }
}

// ---------- add + layernorm (one wave per 256-wide row) ----------
__global__ __launch_bounds__(256) void addln_kernel(const float* __restrict__ X,
    const float* __restrict__ Y, const float* __restrict__ gw,
    const float* __restrict__ bw, float* __restrict__ Out){
  int wave = threadIdx.x >> 6, lane = threadIdx.x & 63;
  long row = (long)blockIdx.x * 4 + wave;
  long base = row * 256 + lane * 4;
  float4 x = *(const float4*)(X + base);
  float4 y = *(const float4*)(Y + base);
  float v0=x.x+y.x, v1=x.y+y.y, v2=x.z+y.z, v3=x.w+y.w;
  float s  = v0+v1+v2+v3;
  float sq = v0*v0+v1*v1+v2*v2+v3*v3;
  #pragma unroll
  for (int off=32; off>0; off>>=1){
    s  += __shfl_xor(s, off);
    sq += __shfl_xor(sq, off);
  }
  float mu  = s * (1.f/256.f);
  float var = sq * (1.f/256.f) - mu*mu;
  float rs  = rsqrtf(var + 1e-5f);
  float4 g4 = *(const float4*)(gw + lane*4);
  float4 b4 = *(const float4*)(bw + lane*4);
  float4 o;
  o.x = (v0-mu)*rs*g4.x + b4.x;
  o.y = (v1-mu)*rs*g4.y + b4.y;
  o.z = (v2-mu)*rs*g4.z + b4.z;
  o.w = (v3-mu)*rs*g4.w + b4.w;
  *(float4*)(Out + base) = o;
}

// ---------- bf16 LDS tile helpers (64B rows, xor-swizzled 16B slots) ----------
__device__ __forceinline__ void stage_copy16(ushort_t* ls, int r, int s, short8 v){
  int byte = r*64 + ((s ^ ((r>>1)&3)) << 4);
  *(short8*)((char*)ls + byte) = v;
}
__device__ __forceinline__ short8 frag_load(const ushort_t* ls, int r, int g){
  int byte = r*64 + ((g ^ ((r>>1)&3)) << 4);
  return *(const short8*)((const char*)ls + byte);
}

// ---------- fp32 LDS fragment read + convert (128B rows, slot ^= row&7) ----------
__device__ __forceinline__ short8 frag_load_f32(const float* ls, int r, int g){
  const char* base = (const char*)ls + r*128;
  int x = r & 7;
  float4 f0 = *(const float4*)(base + ((((2*g)  ^ x)) << 4));
  float4 f1 = *(const float4*)(base + ((((2*g+1)^ x)) << 4));
  uint4 u;
  u.x = packbf2(f0.x, f0.y); u.y = packbf2(f0.z, f0.w);
  u.z = packbf2(f1.x, f1.y); u.w = packbf2(f1.z, f1.w);
  return __builtin_bit_cast(short8, u);
}

// ---------- DMA-staged GEMM, 64m x 128n tile, 4 waves (2m x 2n), depth-2 ----------
// 16 KB LDS -> 4 blocks/CU = 4 INDEPENDENT barrier groups (stall de-correlation).
template<bool RELU, bool OUT_BF16>
__global__ __launch_bounds__(256) void gemm_dma3_kernel(const float* __restrict__ A,
    const ushort_t* __restrict__ Wbf, const float* __restrict__ bias,
    void* __restrict__ Cout, int M, int N, int K){
  __shared__ float    ldsA[2][2048];  // 2 x 8 KB [64r][32c] fp32, slot^(r&7)
  __shared__ ushort_t ldsB[2][4096];  // 2 x 8 KB [128r][32c] bf16, slot^((r>>1)&3)
  const int t = threadIdx.x;
  const int lane = t & 63, wave = t >> 6;
  const int wm = wave >> 1, wn = wave & 1;
  const long rowA0 = (long)blockIdx.x * 64;
  const long rowB0 = (long)blockIdx.y * 128;
  const int rr = lane & 15, g = lane >> 4;
  const int arow_in = lane >> 3;                 // 0..7
  const int aslot   = (lane & 7) ^ (arow_in & 7);
  const int brow_in = lane >> 2;                 // 0..15
  const int bslot   = lane & 3;
  floatx4 acc[2][4] = {};
  const int nsteps = K >> 5;

  #define ISSUE3(kk, buf) do { \
    _Pragma("unroll") \
    for (int c=0;c<2;++c){ \
      int ar_ = wave*16 + c*8 + arow_in; \
      gload16(A + (rowA0 + ar_)*(long)K + (kk) + aslot*4, \
              &ldsA[buf][(wave*16 + c*8)*32]); \
    } \
    _Pragma("unroll") \
    for (int c=0;c<2;++c){ \
      int br_ = wave*32 + c*16 + brow_in; \
      const ushort_t* bs_ = Wbf + (rowB0 + br_)*(long)K + (kk) + (bslot ^ ((br_>>1)&3))*8; \
      gload16(bs_, (char*)ldsB[buf] + (wave*32 + c*16)*64); \
    } \
  } while(0)

  ISSUE3(0, 0);
  if (nsteps > 1) ISSUE3(32, 1);

  for (int k = 0; k < nsteps; ++k){
    if (k < nsteps-1) asm volatile("s_waitcnt vmcnt(4)" ::: "memory");
    else              asm volatile("s_waitcnt vmcnt(0)" ::: "memory");
    FENCED_BARRIER();
    const float*    lA = ldsA[k & 1];
    const ushort_t* lB = ldsB[k & 1];
    short8 af[2], bfr[4];
    #pragma unroll
    for (int mi=0;mi<2;++mi) af[mi]  = frag_load_f32(lA, wm*32 + mi*16 + rr, g);
    #pragma unroll
    for (int ni=0;ni<4;++ni) bfr[ni] = frag_load(lB, wn*64 + ni*16 + rr, g);
    #pragma unroll
    for (int mi=0;mi<2;++mi)
      #pragma unroll
      for (int ni=0;ni<4;++ni)
        acc[mi][ni] = __builtin_amdgcn_mfma_f32_16x16x32_bf16(af[mi], bfr[ni], acc[mi][ni], 0, 0, 0);
    FENCED_BARRIER();
    if (k + 2 < nsteps) ISSUE3((k+2)*32, k & 1);
  }
  #undef ISSUE3

  const int cg = lane >> 4;
  #pragma unroll
  for (int ni=0;ni<4;++ni){
    long n = rowB0 + wn*64 + ni*16 + (lane & 15);
    float bv = bias[n];
    #pragma unroll
    for (int mi=0;mi<2;++mi){
      long m = rowA0 + wm*32 + mi*16 + cg*4;
      #pragma unroll
      for (int r2=0;r2<4;++r2){
        float v = acc[mi][ni][r2] + bv;
        if (RELU) v = fmaxf(v, 0.f);
        if (OUT_BF16) ((ushort_t*)Cout)[(m+r2)*N + n] = f2bf(v);
        else          ((float*)Cout)[(m+r2)*N + n] = v;
      }
    }
  }
}

// ---------- MFMA flash attention (bf16 QK / V inputs) ----------
__global__ __launch_bounds__(256) void attn_mfma_kernel(const ushort_t* __restrict__ QK,
    const ushort_t* __restrict__ V, float* __restrict__ O){
  __shared__ ushort_t lsQ[4096];
  __shared__ ushort_t lsK[1024];
  __shared__ ushort_t lsVT[1024];
  __shared__ ushort_t lsP[4096];
  const int bh = blockIdx.y, b = bh >> 3, h = bh & 7;
  const int qt0 = blockIdx.x * 128;
  const int t = threadIdx.x, lane = t & 63, w = t >> 6;
  const int rr = lane & 15, g = lane >> 4;
  const float csc = 0.25506332f;   // log2(e)/sqrt(32)

  const ushort_t* qbase = QK + ((long)b*1024 + qt0)*512 + h*32;
  #pragma unroll
  for (int j=0;j<2;++j){
    int i = t + j*256; int r = i>>2, s = i&3;
    short8 v = *(const short8*)(qbase + (long)r*512 + s*8);
    stage_copy16(lsQ, r, s, v);
  }
  __syncthreads();
  short8 bq[2];
  bq[0] = frag_load(lsQ, w*32 + rr, g);
  bq[1] = frag_load(lsQ, w*32 + 16 + rr, g);

  floatx4 accO[2][2] = {};
  float rsum[2] = {0.f, 0.f};
  const ushort_t* kbase = QK + (long)b*1024*512 + 256 + h*32;
  const ushort_t* vbase = V  + (long)b*1024*256 + h*32;

  for (int kt = 0; kt < 1024; kt += 32){
    __syncthreads();
    if (t < 128){
      int r = t >> 2, s = t & 3;
      short8 v = *(const short8*)(kbase + (long)(kt + r)*512 + s*8);
      stage_copy16(lsK, r, s, v);
    }
    {
      int kk = t >> 3, d4 = t & 7;
      ushortx4 vv = *(const ushortx4*)(vbase + (long)(kt + kk)*256 + d4*4);
      #pragma unroll
      for (int j=0;j<4;++j){
        int d = d4*4 + j;
        int cb = kk*2;
        int byte = d*64 + ((((cb>>4) ^ ((d>>1)&3)) << 4) | (cb & 15));
        *(ushort_t*)((char*)lsVT + byte) = vv[j];
      }
    }
    __syncthreads();
    floatx4 accS[2][2] = {};
    short8 ak0 = frag_load(lsK, rr, g);
    short8 ak1 = frag_load(lsK, 16 + rr, g);
    accS[0][0] = __builtin_amdgcn_mfma_f32_16x16x32_bf16(ak0, bq[0], accS[0][0], 0,0,0);
    accS[0][1] = __builtin_amdgcn_mfma_f32_16x16x32_bf16(ak0, bq[1], accS[0][1], 0,0,0);
    accS[1][0] = __builtin_amdgcn_mfma_f32_16x16x32_bf16(ak1, bq[0], accS[1][0], 0,0,0);
    accS[1][1] = __builtin_amdgcn_mfma_f32_16x16x32_bf16(ak1, bq[1], accS[1][1], 0,0,0);
    #pragma unroll
    for (int mi=0;mi<2;++mi){
      #pragma unroll
      for (int ni=0;ni<2;++ni){
        float p0 = exp2f(accS[mi][ni][0]*csc);
        float p1 = exp2f(accS[mi][ni][1]*csc);
        float p2 = exp2f(accS[mi][ni][2]*csc);
        float p3 = exp2f(accS[mi][ni][3]*csc);
        rsum[ni] += (p0+p1)+(p2+p3);
        int q   = w*32 + ni*16 + rr;
        int k0b = (mi*16 + g*4)*2;
        int byte = q*64 + ((((k0b>>4) ^ ((q>>1)&3)) << 4) | (k0b & 15));
        uint2 u; u.x = packbf2(p0,p1); u.y = packbf2(p2,p3);
        *(uint2*)((char*)lsP + byte) = u;
      }
    }
    short8 av0 = frag_load(lsVT, rr, g);
    short8 av1 = frag_load(lsVT, 16 + rr, g);
    short8 bp0 = frag_load(lsP, w*32 + rr, g);
    short8 bp1 = frag_load(lsP, w*32 + 16 + rr, g);
    accO[0][0] = __builtin_amdgcn_mfma_f32_16x16x32_bf16(av0, bp0, accO[0][0], 0,0,0);
    accO[0][1] = __builtin_amdgcn_mfma_f32_16x16x32_bf16(av0, bp1, accO[0][1], 0,0,0);
    accO[1][0] = __builtin_amdgcn_mfma_f32_16x16x32_bf16(av1, bp0, accO[1][0], 0,0,0);
    accO[1][1] = __builtin_amdgcn_mfma_f32_16x16x32_bf16(av1, bp1, accO[1][1], 0,0,0);
  }
  #pragma unroll
  for (int ni=0;ni<2;++ni){
    rsum[ni] += __shfl_xor(rsum[ni], 16);
    rsum[ni] += __shfl_xor(rsum[ni], 32);
    float inv = 1.f / rsum[ni];
    int q = qt0 + w*32 + ni*16 + rr;
    float* op = O + ((long)b*1024 + q)*256 + h*32;
    #pragma unroll
    for (int mi=0;mi<2;++mi){
      #pragma unroll
      for (int r2=0;r2<4;++r2){
        int d = mi*16 + g*4 + r2;
        op[d] = accO[mi][ni][r2] * inv;
      }
    }
  }
}

// ---------- multi-scale deformable sampling (branch-free clamped gathers) ----------
__global__ __launch_bounds__(256) void deform_kernel(const ushort_t* __restrict__ val,
    const float* __restrict__ offaw, const float* __restrict__ refp,
    float* __restrict__ Out){
  __shared__ float s_cat[1536], s_ref[32];
  const int t = threadIdx.x;
  const long q0 = (long)blockIdx.x * 4;
  const float* srcOA = offaw + q0*384;
  *(float4*)(s_cat + t*4) = *(const float4*)(srcOA + t*4);
  if (t < 128) *(float4*)(s_cat + 1024 + t*4) = *(const float4*)(srcOA + 1024 + t*4);
  if (t < 32)  s_ref[t] = refp[q0*8 + t];
  __syncthreads();
  const int qi = t >> 6, tl = t & 63;
  const int h = tl >> 3, dq = (tl & 7) << 2;
  const int bq = (int)q0 + qi;
  const int b = bq >> 10;
  const float* offp = s_cat + qi*384 + h*32;
  const float* awp  = s_cat + qi*384 + 256 + h*16;
  const float* refq = s_ref + qi*8;
  float mx = -1e30f;
  #pragma unroll
  for (int i=0;i<16;++i) mx = fmaxf(mx, awp[i]);
  float p[16], sum = 0.f;
  #pragma unroll
  for (int i=0;i<16;++i){ p[i] = expf(awp[i]-mx); sum += p[i]; }
  float inv = 1.f/sum;
  const long vb = (long)b*21760*256 + h*32 + dq;
  const int Dim[4] = {128,64,32,16};
  const int St[4]  = {0,16384,20480,21504};
  float a0=0.f, a1=0.f, a2=0.f, a3=0.f;
  #pragma unroll
  for (int l=0;l<4;++l){
    const int Wl = Dim[l], Hl = Dim[l], st = St[l];
    float rx = refq[2*l], ry = refq[2*l+1];
    #pragma unroll
    for (int pp=0;pp<4;++pp){
      float x = rx*(float)Wl + offp[l*8+pp*2]   - 0.5f;
      float y = ry*(float)Hl + offp[l*8+pp*2+1] - 0.5f;
      float xf = floorf(x), yf = floorf(y);
      int x0 = (int)xf, y0 = (int)yf;
      float tx = x - xf, ty = y - yf;
      float s0=0.f,s1=0.f,s2=0.f,s3=0.f;
      #define CORNER(XI, YI, WGT) { \
        int xi_ = (XI), yi_ = (YI); \
        bool valid_ = (xi_ >= 0) & (xi_ < Wl) & (yi_ >= 0) & (yi_ < Hl); \
        int xc_ = min(max(xi_, 0), Wl-1), yc_ = min(max(yi_, 0), Hl-1); \
        ushortx4 u = *(const ushortx4*)(val + vb + (long)(st + yc_*Wl + xc_)*256); \
        float wq = valid_ ? (WGT) : 0.f; \
        s0 += wq*bf2f(u[0]); s1 += wq*bf2f(u[1]); \
        s2 += wq*bf2f(u[2]); s3 += wq*bf2f(u[3]); \
      }
      CORNER(x0,   y0,   (1.f-tx)*(1.f-ty));
      CORNER(x0+1, y0,   tx*(1.f-ty));
      CORNER(x0,   y0+1, (1.f-tx)*ty);
      CORNER(x0+1, y0+1, tx*ty);
      #undef CORNER
      float pw = p[l*4+pp];
      a0 += pw*s0; a1 += pw*s1; a2 += pw*s2; a3 += pw*s3;
    }
  }
  float4 o; o.x=a0*inv; o.y=a1*inv; o.z=a2*inv; o.w=a3*inv;
  *(float4*)(Out + (long)bq*256 + h*32 + dq) = o;
}

// ---------------- host launcher ----------------
extern "C" void kernel_launch(void* const* d_in, const int* in_sizes, int n_in,
                              void* d_out, int out_size, void* d_ws, size_t ws_size,
                              hipStream_t stream){
  (void)in_sizes; (void)n_in; (void)out_size; (void)ws_size;
  const float* tgt   = (const float*)d_in[0];
  const float* qpos  = (const float*)d_in[1];
  const float* refp  = (const float*)d_in[2];
  const float* src   = (const float*)d_in[3];
  const float* w_in  = (const float*)d_in[4];
  const float* b_in  = (const float*)d_in[5];
  const float* w_out = (const float*)d_in[6];
  const float* b_out = (const float*)d_in[7];
  const float* ln1g  = (const float*)d_in[8];
  const float* ln1b  = (const float*)d_in[9];
  const float* ln2g  = (const float*)d_in[10];
  const float* ln2b  = (const float*)d_in[11];
  const float* ln3g  = (const float*)d_in[12];
  const float* ln3b  = (const float*)d_in[13];
  const float* w_val = (const float*)d_in[14];
  const float* b_val = (const float*)d_in[15];
  const float* w_off = (const float*)d_in[16];
  const float* b_off = (const float*)d_in[17];
  const float* w_attw= (const float*)d_in[18];
  const float* b_attw= (const float*)d_in[19];
  const float* w_oc  = (const float*)d_in[20];
  const float* b_oc  = (const float*)d_in[21];
  const float* w1    = (const float*)d_in[22];
  const float* b1    = (const float*)d_in[23];
  const float* w2    = (const float*)d_in[24];
  const float* b2    = (const float*)d_in[25];

  float* ws = (float*)d_ws;
  ushort_t* bufWbf = (ushort_t*)ws;               // 1,015,808 ushorts -> 507,904 f
  float* bufBOA = ws + 507904;                    // 384 (b_off|b_attw)
  float* bufQ   = ws + 524288;                    // 2M (tgt+qpos), dead after q|k
  float* bufOA  = ws + 524288;                    // 3.14M (off|aw), lives steps 9-10
  ushort_t* bufQK = (ushort_t*)(ws + 2621440);    // bf16 8192x512, dead after attn
  ushort_t* bufV  = (ushort_t*)(ws + 4718592);    // bf16 8192x256
  float* bufO   = ws + 5767168;                   // 2M
  float* bufT2  = ws + 7864320;                   // 2M (also query2 temp)
  float* bufTg1 = ws + 9961472;                   // 2M
  float* bufTg2 = ws + 12058624;                  // 2M
  ushort_t* bufVal = (ushort_t*)(ws + 16777216);  // bf16 value (89MB)
  float* bufH   = ws + 16777216;                  // FFN hidden, reuses bufVal region
  float* outF   = (float*)d_out;

  const ushort_t* winbf    = bufWbf;              // w_in rows 0..767
  const ushort_t* winvbf   = bufWbf + 131072;     // w_in rows 512..767
  const ushort_t* wvalbf   = bufWbf + 196608;
  const ushort_t* woutbf   = bufWbf + 262144;
  const ushort_t* wocbf    = bufWbf + 327680;
  const ushort_t* w1bf     = bufWbf + 393216;
  const ushort_t* w2bf     = bufWbf + 655360;
  const ushort_t* woffawbf = bufWbf + 917504;     // 384 rows: w_off(256) | w_attw(128)

  dim3 B256(256);
  // 0a. convert all weights to bf16
  convert_w_kernel<<<dim3(992), B256, 0, stream>>>(w_in, w_val, w_out, w_oc, w1, w2, w_off, w_attw, bufWbf);
  // 0b. pack biases b_off|b_attw (fp32, 384)
  pack_bias_kernel<<<dim3(1), B256, 0, stream>>>(b_off, b_attw, bufBOA);
  // 1. q = tgt + query_pos
  add_kernel<<<dim3(2048), B256, 0, stream>>>(tgt, qpos, bufQ, 524288);
  // 2. q|k projection -> bf16 (w_in rows 0..511), N=512
  gemm_dma3_kernel<false,true><<<dim3(128,4), B256, 0, stream>>>(bufQ, winbf, b_in, bufQK, 8192, 512, 256);
  // 3. v projection -> bf16 (w_in rows 512..767)
  gemm_dma3_kernel<false,true><<<dim3(128,2), B256, 0, stream>>>(tgt, winvbf, b_in + 512, bufV, 8192, 256, 256);
  // 4. attention (MFMA flash, bf16 inputs)
  attn_mfma_kernel<<<dim3(8,64), B256, 0, stream>>>(bufQK, bufV, bufO);
  // 5. output projection
  gemm_dma3_kernel<false,false><<<dim3(128,2), B256, 0, stream>>>(bufO, woutbf, b_out, bufT2, 8192, 256, 256);
  // 6. tgt1 = LN2(tgt + t2)
  addln_kernel<<<dim3(2048), B256, 0, stream>>>(tgt, bufT2, ln2g, ln2b, bufTg1);
  // 7. value projection (bf16 out) -- dma3, 4 blocks/CU occupancy probe
  gemm_dma3_kernel<false,true><<<dim3(2720,2), B256, 0, stream>>>(src, wvalbf, b_val, bufVal, 174080, 256, 256);
  // 8. query2 = tgt1 + query_pos (into bufT2, free at this point)
  add_kernel<<<dim3(2048), B256, 0, stream>>>(bufTg1, qpos, bufT2, 524288);
  // 9. sampling offsets + attn-weight logits in ONE GEMM (N=384, bf16 weights)
  gemm_dma3_kernel<false,false><<<dim3(128,3), B256, 0, stream>>>(bufT2, woffawbf, bufBOA, bufOA, 8192, 384, 256);
  // 10. deformable sampling
  deform_kernel<<<dim3(2048), B256, 0, stream>>>(bufVal, bufOA, refp, bufO);
  // 11. output-context projection
  gemm_dma3_kernel<false,false><<<dim3(128,2), B256, 0, stream>>>(bufO, wocbf, b_oc, bufT2, 8192, 256, 256);
  // 12. tgt2 = LN1(tgt1 + ca)
  addln_kernel<<<dim3(2048), B256, 0, stream>>>(bufTg1, bufT2, ln1g, ln1b, bufTg2);
  // 13. FFN up + relu -- dma3, 4 blocks/CU occupancy probe
  gemm_dma3_kernel<true,false><<<dim3(128,8), B256, 0, stream>>>(bufTg2, w1bf, b1, bufH, 8192, 1024, 256);
  // 14. FFN down (K=1024)
  gemm_dma3_kernel<false,false><<<dim3(128,2), B256, 0, stream>>>(bufH, w2bf, b2, bufT2, 8192, 256, 1024);
  // 15. out = LN3(tgt2 + t2)
  addln_kernel<<<dim3(2048), B256, 0, stream>>>(bufTg2, bufT2, ln3g, ln3b, outF);
}

// Round 17
// 285.172 us; speedup vs baseline: 1.0724x; 1.0724x over previous
//
#include <hip/hip_runtime.h>

typedef unsigned short ushort_t;
typedef unsigned int uint_t;
typedef __attribute__((ext_vector_type(8))) short short8;
typedef __attribute__((ext_vector_type(4))) float floatx4;
typedef __attribute__((ext_vector_type(4))) unsigned short ushortx4;

// ---------- bf16 helpers ----------
__device__ __forceinline__ ushort_t f2bf(float f){
  uint_t u = __builtin_bit_cast(uint_t, f);
  u += 0x7FFFu + ((u >> 16) & 1u);          // RNE
  return (ushort_t)(u >> 16);
}
__device__ __forceinline__ float bf2f(ushort_t u){
  uint_t x = ((uint_t)u) << 16;
  return __builtin_bit_cast(float, x);
}
__device__ __forceinline__ uint_t packbf2(float a, float b){
  return (uint_t)f2bf(a) | ((uint_t)f2bf(b) << 16);
}

// ---------- global -> LDS direct DMA (16B per lane, dest = base + lane*16) ----------
__device__ __forceinline__ void gload16(const void* g, void* l){
  __builtin_amdgcn_global_load_lds(
      (const __attribute__((address_space(1))) void*)g,
      (__attribute__((address_space(3))) void*)l, 16, 0, 0);
}

// barrier that is ALSO a compiler memory fence (raw s_barrier builtin is NOT:
// LLVM may move LDS/global_load_lds ops across it -> replay-dependent races).
#define FENCED_BARRIER() asm volatile("s_barrier" ::: "memory")

// ---------- weight fp32 -> bf16 pre-convert ----------
// dst (ushort elems): w_in(196608) | w_val(65536) | w_out(65536) | w_oc(65536)
//                   | w1(262144) | w2(262144) | w_off(65536) | w_attw(32768)
__global__ __launch_bounds__(256) void convert_w_kernel(const float* __restrict__ w_in,
    const float* __restrict__ w_val, const float* __restrict__ w_out,
    const float* __restrict__ w_oc, const float* __restrict__ w1,
    const float* __restrict__ w2, const float* __restrict__ w_off,
    const float* __restrict__ w_attw, ushort_t* __restrict__ dst){
  int j = (blockIdx.x*256 + threadIdx.x) * 4;
  if (j >= 1015808) return;
  const float* src; int off;
  if      (j < 196608){ src = w_in;   off = 0;      }
  else if (j < 262144){ src = w_val;  off = 196608; }
  else if (j < 327680){ src = w_out;  off = 262144; }
  else if (j < 393216){ src = w_oc;   off = 327680; }
  else if (j < 655360){ src = w1;     off = 393216; }
  else if (j < 917504){ src = w2;     off = 655360; }
  else if (j < 983040){ src = w_off;  off = 917504; }
  else                { src = w_attw; off = 983040; }
  float4 v = *(const float4*)(src + (j - off));
  uint2 u; u.x = packbf2(v.x, v.y); u.y = packbf2(v.z, v.w);
  *(uint2*)(dst + j) = u;
}

// ---------- pack b_off | b_attw into one fp32 vector (384) ----------
__global__ __launch_bounds__(256) void pack_bias_kernel(const float* __restrict__ b_off,
    const float* __restrict__ b_attw, float* __restrict__ dst){
  int t = threadIdx.x;
  dst[t] = b_off[t];
  if (t < 128) dst[256 + t] = b_attw[t];
}

// ---------- elementwise add (float4) ----------
__global__ __launch_bounds__(256) void add_kernel(const float* __restrict__ a,
    const float* __restrict__ b, float* __restrict__ c, int n4){
  int i = blockIdx.x * 256 + threadIdx.x;
  if (i < n4){
    float4 x = ((const float4*)a)[i];
    float4 y = ((const float4*)b)[i];
    float4 z; z.x=x.x+y.x; z.y=x.y+y.y; z.z=x.z+y.z; z.w=x.w+y.w;
    ((float4*)c)[i] = z;
  }
}

// ---------- add + layernorm (one wave per 256-wide row) ----------
__global__ __launch_bounds__(256) void addln_kernel(const float* __restrict__ X,
    const float* __restrict__ Y, const float* __restrict__ gw,
    const float* __restrict__ bw, float* __restrict__ Out){
  int wave = threadIdx.x >> 6, lane = threadIdx.x & 63;
  long row = (long)blockIdx.x * 4 + wave;
  long base = row * 256 + lane * 4;
  float4 x = *(const float4*)(X + base);
  float4 y = *(const float4*)(Y + base);
  float v0=x.x+y.x, v1=x.y+y.y, v2=x.z+y.z, v3=x.w+y.w;
  float s  = v0+v1+v2+v3;
  float sq = v0*v0+v1*v1+v2*v2+v3*v3;
  #pragma unroll
  for (int off=32; off>0; off>>=1){
    s  += __shfl_xor(s, off);
    sq += __shfl_xor(sq, off);
  }
  float mu  = s * (1.f/256.f);
  float var = sq * (1.f/256.f) - mu*mu;
  float rs  = rsqrtf(var + 1e-5f);
  float4 g4 = *(const float4*)(gw + lane*4);
  float4 b4 = *(const float4*)(bw + lane*4);
  float4 o;
  o.x = (v0-mu)*rs*g4.x + b4.x;
  o.y = (v1-mu)*rs*g4.y + b4.y;
  o.z = (v2-mu)*rs*g4.z + b4.z;
  o.w = (v3-mu)*rs*g4.w + b4.w;
  *(float4*)(Out + base) = o;
}

// ---------- bf16 LDS tile helpers (64B rows, xor-swizzled 16B slots) ----------
__device__ __forceinline__ void stage_copy16(ushort_t* ls, int r, int s, short8 v){
  int byte = r*64 + ((s ^ ((r>>1)&3)) << 4);
  *(short8*)((char*)ls + byte) = v;
}
__device__ __forceinline__ short8 frag_load(const ushort_t* ls, int r, int g){
  int byte = r*64 + ((g ^ ((r>>1)&3)) << 4);
  return *(const short8*)((const char*)ls + byte);
}

// ---------- fp32 LDS fragment read + convert (128B rows, slot ^= row&7) ----------
__device__ __forceinline__ short8 frag_load_f32(const float* ls, int r, int g){
  const char* base = (const char*)ls + r*128;
  int x = r & 7;
  float4 f0 = *(const float4*)(base + ((((2*g)  ^ x)) << 4));
  float4 f1 = *(const float4*)(base + ((((2*g+1)^ x)) << 4));
  uint4 u;
  u.x = packbf2(f0.x, f0.y); u.y = packbf2(f0.z, f0.w);
  u.z = packbf2(f1.x, f1.y); u.w = packbf2(f1.z, f1.w);
  return __builtin_bit_cast(short8, u);
}

// ---------- DMA-staged GEMM, 64m x 128n tile, 4 waves (2m x 2n), depth-2 ----------
template<bool RELU, bool OUT_BF16>
__global__ __launch_bounds__(256) void gemm_dma3_kernel(const float* __restrict__ A,
    const ushort_t* __restrict__ Wbf, const float* __restrict__ bias,
    void* __restrict__ Cout, int M, int N, int K){
  __shared__ float    ldsA[2][2048];  // 2 x 8 KB [64r][32c] fp32, slot^(r&7)
  __shared__ ushort_t ldsB[2][4096];  // 2 x 8 KB [128r][32c] bf16, slot^((r>>1)&3)
  const int t = threadIdx.x;
  const int lane = t & 63, wave = t >> 6;
  const int wm = wave >> 1, wn = wave & 1;
  const long rowA0 = (long)blockIdx.x * 64;
  const long rowB0 = (long)blockIdx.y * 128;
  const int rr = lane & 15, g = lane >> 4;
  const int arow_in = lane >> 3;                 // 0..7
  const int aslot   = (lane & 7) ^ (arow_in & 7);
  const int brow_in = lane >> 2;                 // 0..15
  const int bslot   = lane & 3;
  floatx4 acc[2][4] = {};
  const int nsteps = K >> 5;

  #define ISSUE3(kk, buf) do { \
    _Pragma("unroll") \
    for (int c=0;c<2;++c){ \
      int ar_ = wave*16 + c*8 + arow_in; \
      gload16(A + (rowA0 + ar_)*(long)K + (kk) + aslot*4, \
              &ldsA[buf][(wave*16 + c*8)*32]); \
    } \
    _Pragma("unroll") \
    for (int c=0;c<2;++c){ \
      int br_ = wave*32 + c*16 + brow_in; \
      const ushort_t* bs_ = Wbf + (rowB0 + br_)*(long)K + (kk) + (bslot ^ ((br_>>1)&3))*8; \
      gload16(bs_, (char*)ldsB[buf] + (wave*32 + c*16)*64); \
    } \
  } while(0)

  ISSUE3(0, 0);
  if (nsteps > 1) ISSUE3(32, 1);

  for (int k = 0; k < nsteps; ++k){
    if (k < nsteps-1) asm volatile("s_waitcnt vmcnt(4)" ::: "memory");
    else              asm volatile("s_waitcnt vmcnt(0)" ::: "memory");
    FENCED_BARRIER();
    const float*    lA = ldsA[k & 1];
    const ushort_t* lB = ldsB[k & 1];
    short8 af[2], bfr[4];
    #pragma unroll
    for (int mi=0;mi<2;++mi) af[mi]  = frag_load_f32(lA, wm*32 + mi*16 + rr, g);
    #pragma unroll
    for (int ni=0;ni<4;++ni) bfr[ni] = frag_load(lB, wn*64 + ni*16 + rr, g);
    #pragma unroll
    for (int mi=0;mi<2;++mi)
      #pragma unroll
      for (int ni=0;ni<4;++ni)
        acc[mi][ni] = __builtin_amdgcn_mfma_f32_16x16x32_bf16(af[mi], bfr[ni], acc[mi][ni], 0, 0, 0);
    FENCED_BARRIER();
    if (k + 2 < nsteps) ISSUE3((k+2)*32, k & 1);
  }
  #undef ISSUE3

  const int cg = lane >> 4;
  #pragma unroll
  for (int ni=0;ni<4;++ni){
    long n = rowB0 + wn*64 + ni*16 + (lane & 15);
    float bv = bias[n];
    #pragma unroll
    for (int mi=0;mi<2;++mi){
      long m = rowA0 + wm*32 + mi*16 + cg*4;
      #pragma unroll
      for (int r2=0;r2<4;++r2){
        float v = acc[mi][ni][r2] + bv;
        if (RELU) v = fmaxf(v, 0.f);
        if (OUT_BF16) ((ushort_t*)Cout)[(m+r2)*N + n] = f2bf(v);
        else          ((float*)Cout)[(m+r2)*N + n] = v;
      }
    }
  }
}

// ---------- DMA-staged GEMM, 128m x 256n tile, 8 waves (2m x 4n), depth-2 ----------
template<bool RELU, bool OUT_BF16>
__global__ __launch_bounds__(512, 4) void gemm_dma2_kernel(const float* __restrict__ A,
    const ushort_t* __restrict__ Wbf, const float* __restrict__ bias,
    void* __restrict__ Cout, int M, int N, int K){
  __shared__ float    ldsA[2][4096];  // 2 x 16 KB [128r][32c] fp32, slot^(r&7)
  __shared__ ushort_t ldsB[2][8192];  // 2 x 16 KB [256r][32c] bf16, slot^((r>>1)&3)
  const int t = threadIdx.x;
  const int lane = t & 63, wave = t >> 6;       // 8 waves
  const int wm = wave >> 2, wn = wave & 3;      // 2m x 4n
  const long rowA0 = (long)blockIdx.x * 128;
  const long n0 = (long)blockIdx.y * 256;
  const int rr = lane & 15, g = lane >> 4;
  const int arow_in = lane >> 3;                 // 0..7
  const int aslot   = (lane & 7) ^ (arow_in & 7);
  const int brow_in = lane >> 2;                 // 0..15
  const int bslot   = lane & 3;
  floatx4 acc[4][4] = {};
  const int nsteps = K >> 5;

  #define ISSUE2(kk, buf) do { \
    _Pragma("unroll") \
    for (int c=0;c<2;++c){ \
      int ar_ = (wave*2 + c)*8 + arow_in; \
      gload16(A + (rowA0 + ar_)*(long)K + (kk) + aslot*4, \
              &ldsA[buf][(wave*2 + c)*8*32]); \
    } \
    _Pragma("unroll") \
    for (int c=0;c<2;++c){ \
      int br_ = (wave*2 + c)*16 + brow_in; \
      const ushort_t* bs_ = Wbf + (n0 + br_)*(long)K + (kk) + (bslot ^ ((br_>>1)&3))*8; \
      gload16(bs_, (char*)ldsB[buf] + (wave*2 + c)*16*64); \
    } \
  } while(0)

  ISSUE2(0, 0);
  if (nsteps > 1) ISSUE2(32, 1);

  for (int k = 0; k < nsteps; ++k){
    if (k < nsteps-1) asm volatile("s_waitcnt vmcnt(4)" ::: "memory");
    else              asm volatile("s_waitcnt vmcnt(0)" ::: "memory");
    FENCED_BARRIER();
    const float*    lA = ldsA[k & 1];
    const ushort_t* lB = ldsB[k & 1];
    short8 af[4], bfr[4];
    #pragma unroll
    for (int mi=0;mi<4;++mi) af[mi]  = frag_load_f32(lA, wm*64 + mi*16 + rr, g);
    #pragma unroll
    for (int ni=0;ni<4;++ni) bfr[ni] = frag_load(lB, wn*64 + ni*16 + rr, g);
    #pragma unroll
    for (int mi=0;mi<4;++mi)
      #pragma unroll
      for (int ni=0;ni<4;++ni)
        acc[mi][ni] = __builtin_amdgcn_mfma_f32_16x16x32_bf16(af[mi], bfr[ni], acc[mi][ni], 0, 0, 0);
    FENCED_BARRIER();
    if (k + 2 < nsteps) ISSUE2((k+2)*32, k & 1);
  }
  #undef ISSUE2

  const int cg = lane >> 4;
  #pragma unroll
  for (int ni=0;ni<4;++ni){
    long n = n0 + wn*64 + ni*16 + (lane & 15);
    float bv = bias[n];
    #pragma unroll
    for (int mi=0;mi<4;++mi){
      long m = rowA0 + wm*64 + mi*16 + cg*4;
      #pragma unroll
      for (int r2=0;r2<4;++r2){
        float v = acc[mi][ni][r2] + bv;
        if (RELU) v = fmaxf(v, 0.f);
        if (OUT_BF16) ((ushort_t*)Cout)[(m+r2)*N + n] = f2bf(v);
        else          ((float*)Cout)[(m+r2)*N + n] = v;
      }
    }
  }
}

// ---------- MFMA flash attention (bf16 QK / V inputs) ----------
__global__ __launch_bounds__(256) void attn_mfma_kernel(const ushort_t* __restrict__ QK,
    const ushort_t* __restrict__ V, float* __restrict__ O){
  __shared__ ushort_t lsQ[4096];
  __shared__ ushort_t lsK[1024];
  __shared__ ushort_t lsVT[1024];
  __shared__ ushort_t lsP[4096];
  const int bh = blockIdx.y, b = bh >> 3, h = bh & 7;
  const int qt0 = blockIdx.x * 128;
  const int t = threadIdx.x, lane = t & 63, w = t >> 6;
  const int rr = lane & 15, g = lane >> 4;
  const float csc = 0.25506332f;   // log2(e)/sqrt(32)

  const ushort_t* qbase = QK + ((long)b*1024 + qt0)*512 + h*32;
  #pragma unroll
  for (int j=0;j<2;++j){
    int i = t + j*256; int r = i>>2, s = i&3;
    short8 v = *(const short8*)(qbase + (long)r*512 + s*8);
    stage_copy16(lsQ, r, s, v);
  }
  __syncthreads();
  short8 bq[2];
  bq[0] = frag_load(lsQ, w*32 + rr, g);
  bq[1] = frag_load(lsQ, w*32 + 16 + rr, g);

  floatx4 accO[2][2] = {};
  float rsum[2] = {0.f, 0.f};
  const ushort_t* kbase = QK + (long)b*1024*512 + 256 + h*32;
  const ushort_t* vbase = V  + (long)b*1024*256 + h*32;

  for (int kt = 0; kt < 1024; kt += 32){
    __syncthreads();
    if (t < 128){
      int r = t >> 2, s = t & 3;
      short8 v = *(const short8*)(kbase + (long)(kt + r)*512 + s*8);
      stage_copy16(lsK, r, s, v);
    }
    {
      int kk = t >> 3, d4 = t & 7;
      ushortx4 vv = *(const ushortx4*)(vbase + (long)(kt + kk)*256 + d4*4);
      #pragma unroll
      for (int j=0;j<4;++j){
        int d = d4*4 + j;
        int cb = kk*2;
        int byte = d*64 + ((((cb>>4) ^ ((d>>1)&3)) << 4) | (cb & 15));
        *(ushort_t*)((char*)lsVT + byte) = vv[j];
      }
    }
    __syncthreads();
    floatx4 accS[2][2] = {};
    short8 ak0 = frag_load(lsK, rr, g);
    short8 ak1 = frag_load(lsK, 16 + rr, g);
    accS[0][0] = __builtin_amdgcn_mfma_f32_16x16x32_bf16(ak0, bq[0], accS[0][0], 0,0,0);
    accS[0][1] = __builtin_amdgcn_mfma_f32_16x16x32_bf16(ak0, bq[1], accS[0][1], 0,0,0);
    accS[1][0] = __builtin_amdgcn_mfma_f32_16x16x32_bf16(ak1, bq[0], accS[1][0], 0,0,0);
    accS[1][1] = __builtin_amdgcn_mfma_f32_16x16x32_bf16(ak1, bq[1], accS[1][1], 0,0,0);
    #pragma unroll
    for (int mi=0;mi<2;++mi){
      #pragma unroll
      for (int ni=0;ni<2;++ni){
        float p0 = exp2f(accS[mi][ni][0]*csc);
        float p1 = exp2f(accS[mi][ni][1]*csc);
        float p2 = exp2f(accS[mi][ni][2]*csc);
        float p3 = exp2f(accS[mi][ni][3]*csc);
        rsum[ni] += (p0+p1)+(p2+p3);
        int q   = w*32 + ni*16 + rr;
        int k0b = (mi*16 + g*4)*2;
        int byte = q*64 + ((((k0b>>4) ^ ((q>>1)&3)) << 4) | (k0b & 15));
        uint2 u; u.x = packbf2(p0,p1); u.y = packbf2(p2,p3);
        *(uint2*)((char*)lsP + byte) = u;
      }
    }
    short8 av0 = frag_load(lsVT, rr, g);
    short8 av1 = frag_load(lsVT, 16 + rr, g);
    short8 bp0 = frag_load(lsP, w*32 + rr, g);
    short8 bp1 = frag_load(lsP, w*32 + 16 + rr, g);
    accO[0][0] = __builtin_amdgcn_mfma_f32_16x16x32_bf16(av0, bp0, accO[0][0], 0,0,0);
    accO[0][1] = __builtin_amdgcn_mfma_f32_16x16x32_bf16(av0, bp1, accO[0][1], 0,0,0);
    accO[1][0] = __builtin_amdgcn_mfma_f32_16x16x32_bf16(av1, bp0, accO[1][0], 0,0,0);
    accO[1][1] = __builtin_amdgcn_mfma_f32_16x16x32_bf16(av1, bp1, accO[1][1], 0,0,0);
  }
  #pragma unroll
  for (int ni=0;ni<2;++ni){
    rsum[ni] += __shfl_xor(rsum[ni], 16);
    rsum[ni] += __shfl_xor(rsum[ni], 32);
    float inv = 1.f / rsum[ni];
    int q = qt0 + w*32 + ni*16 + rr;
    float* op = O + ((long)b*1024 + q)*256 + h*32;
    #pragma unroll
    for (int mi=0;mi<2;++mi){
      #pragma unroll
      for (int r2=0;r2<4;++r2){
        int d = mi*16 + g*4 + r2;
        op[d] = accO[mi][ni][r2] * inv;
      }
    }
  }
}

// ---------- multi-scale deformable sampling (branch-free clamped gathers) ----------
__global__ __launch_bounds__(256) void deform_kernel(const ushort_t* __restrict__ val,
    const float* __restrict__ offaw, const float* __restrict__ refp,
    float* __restrict__ Out){
  __shared__ float s_cat[1536], s_ref[32];
  const int t = threadIdx.x;
  const long q0 = (long)blockIdx.x * 4;
  const float* srcOA = offaw + q0*384;
  *(float4*)(s_cat + t*4) = *(const float4*)(srcOA + t*4);
  if (t < 128) *(float4*)(s_cat + 1024 + t*4) = *(const float4*)(srcOA + 1024 + t*4);
  if (t < 32)  s_ref[t] = refp[q0*8 + t];
  __syncthreads();
  const int qi = t >> 6, tl = t & 63;
  const int h = tl >> 3, dq = (tl & 7) << 2;
  const int bq = (int)q0 + qi;
  const int b = bq >> 10;
  const float* offp = s_cat + qi*384 + h*32;
  const float* awp  = s_cat + qi*384 + 256 + h*16;
  const float* refq = s_ref + qi*8;
  float mx = -1e30f;
  #pragma unroll
  for (int i=0;i<16;++i) mx = fmaxf(mx, awp[i]);
  float p[16], sum = 0.f;
  #pragma unroll
  for (int i=0;i<16;++i){ p[i] = expf(awp[i]-mx); sum += p[i]; }
  float inv = 1.f/sum;
  const long vb = (long)b*21760*256 + h*32 + dq;
  const int Dim[4] = {128,64,32,16};
  const int St[4]  = {0,16384,20480,21504};
  float a0=0.f, a1=0.f, a2=0.f, a3=0.f;
  #pragma unroll
  for (int l=0;l<4;++l){
    const int Wl = Dim[l], Hl = Dim[l], st = St[l];
    float rx = refq[2*l], ry = refq[2*l+1];
    #pragma unroll
    for (int pp=0;pp<4;++pp){
      float x = rx*(float)Wl + offp[l*8+pp*2]   - 0.5f;
      float y = ry*(float)Hl + offp[l*8+pp*2+1] - 0.5f;
      float xf = floorf(x), yf = floorf(y);
      int x0 = (int)xf, y0 = (int)yf;
      float tx = x - xf, ty = y - yf;
      float s0=0.f,s1=0.f,s2=0.f,s3=0.f;
      #define CORNER(XI, YI, WGT) { \
        int xi_ = (XI), yi_ = (YI); \
        bool valid_ = (xi_ >= 0) & (xi_ < Wl) & (yi_ >= 0) & (yi_ < Hl); \
        int xc_ = min(max(xi_, 0), Wl-1), yc_ = min(max(yi_, 0), Hl-1); \
        ushortx4 u = *(const ushortx4*)(val + vb + (long)(st + yc_*Wl + xc_)*256); \
        float wq = valid_ ? (WGT) : 0.f; \
        s0 += wq*bf2f(u[0]); s1 += wq*bf2f(u[1]); \
        s2 += wq*bf2f(u[2]); s3 += wq*bf2f(u[3]); \
      }
      CORNER(x0,   y0,   (1.f-tx)*(1.f-ty));
      CORNER(x0+1, y0,   tx*(1.f-ty));
      CORNER(x0,   y0+1, (1.f-tx)*ty);
      CORNER(x0+1, y0+1, tx*ty);
      #undef CORNER
      float pw = p[l*4+pp];
      a0 += pw*s0; a1 += pw*s1; a2 += pw*s2; a3 += pw*s3;
    }
  }
  float4 o; o.x=a0*inv; o.y=a1*inv; o.z=a2*inv; o.w=a3*inv;
  *(float4*)(Out + (long)bq*256 + h*32 + dq) = o;
}

// ---------------- host launcher ----------------
extern "C" void kernel_launch(void* const* d_in, const int* in_sizes, int n_in,
                              void* d_out, int out_size, void* d_ws, size_t ws_size,
                              hipStream_t stream){
  (void)in_sizes; (void)n_in; (void)out_size; (void)ws_size;
  const float* tgt   = (const float*)d_in[0];
  const float* qpos  = (const float*)d_in[1];
  const float* refp  = (const float*)d_in[2];
  const float* src   = (const float*)d_in[3];
  const float* w_in  = (const float*)d_in[4];
  const float* b_in  = (const float*)d_in[5];
  const float* w_out = (const float*)d_in[6];
  const float* b_out = (const float*)d_in[7];
  const float* ln1g  = (const float*)d_in[8];
  const float* ln1b  = (const float*)d_in[9];
  const float* ln2g  = (const float*)d_in[10];
  const float* ln2b  = (const float*)d_in[11];
  const float* ln3g  = (const float*)d_in[12];
  const float* ln3b  = (const float*)d_in[13];
  const float* w_val = (const float*)d_in[14];
  const float* b_val = (const float*)d_in[15];
  const float* w_off = (const float*)d_in[16];
  const float* b_off = (const float*)d_in[17];
  const float* w_attw= (const float*)d_in[18];
  const float* b_attw= (const float*)d_in[19];
  const float* w_oc  = (const float*)d_in[20];
  const float* b_oc  = (const float*)d_in[21];
  const float* w1    = (const float*)d_in[22];
  const float* b1    = (const float*)d_in[23];
  const float* w2    = (const float*)d_in[24];
  const float* b2    = (const float*)d_in[25];

  float* ws = (float*)d_ws;
  ushort_t* bufWbf = (ushort_t*)ws;               // 1,015,808 ushorts -> 507,904 f
  float* bufBOA = ws + 507904;                    // 384 (b_off|b_attw)
  float* bufQ   = ws + 524288;                    // 2M (tgt+qpos), dead after q|k
  float* bufOA  = ws + 524288;                    // 3.14M (off|aw), lives steps 9-10
  ushort_t* bufQK = (ushort_t*)(ws + 2621440);    // bf16 8192x512, dead after attn
  ushort_t* bufV  = (ushort_t*)(ws + 4718592);    // bf16 8192x256
  float* bufO   = ws + 5767168;                   // 2M
  float* bufT2  = ws + 7864320;                   // 2M (also query2 temp)
  float* bufTg1 = ws + 9961472;                   // 2M
  float* bufTg2 = ws + 12058624;                  // 2M
  ushort_t* bufVal = (ushort_t*)(ws + 16777216);  // bf16 value (89MB)
  float* bufH   = ws + 16777216;                  // FFN hidden, reuses bufVal region
  float* outF   = (float*)d_out;

  const ushort_t* winbf    = bufWbf;              // w_in rows 0..767
  const ushort_t* winvbf   = bufWbf + 131072;     // w_in rows 512..767
  const ushort_t* wvalbf   = bufWbf + 196608;
  const ushort_t* woutbf   = bufWbf + 262144;
  const ushort_t* wocbf    = bufWbf + 327680;
  const ushort_t* w1bf     = bufWbf + 393216;
  const ushort_t* w2bf     = bufWbf + 655360;
  const ushort_t* woffawbf = bufWbf + 917504;     // 384 rows: w_off(256) | w_attw(128)

  dim3 B256(256), B512(512);
  // 0a. convert all weights to bf16
  convert_w_kernel<<<dim3(992), B256, 0, stream>>>(w_in, w_val, w_out, w_oc, w1, w2, w_off, w_attw, bufWbf);
  // 0b. pack biases b_off|b_attw (fp32, 384)
  pack_bias_kernel<<<dim3(1), B256, 0, stream>>>(b_off, b_attw, bufBOA);
  // 1. q = tgt + query_pos
  add_kernel<<<dim3(2048), B256, 0, stream>>>(tgt, qpos, bufQ, 524288);
  // 2. q|k projection -> bf16 (w_in rows 0..511), N=512
  gemm_dma3_kernel<false,true><<<dim3(128,4), B256, 0, stream>>>(bufQ, winbf, b_in, bufQK, 8192, 512, 256);
  // 3. v projection -> bf16 (w_in rows 512..767)
  gemm_dma3_kernel<false,true><<<dim3(128,2), B256, 0, stream>>>(tgt, winvbf, b_in + 512, bufV, 8192, 256, 256);
  // 4. attention (MFMA flash, bf16 inputs)
  attn_mfma_kernel<<<dim3(8,64), B256, 0, stream>>>(bufQK, bufV, bufO);
  // 5. output projection
  gemm_dma3_kernel<false,false><<<dim3(128,2), B256, 0, stream>>>(bufO, woutbf, b_out, bufT2, 8192, 256, 256);
  // 6. tgt1 = LN2(tgt + t2)
  addln_kernel<<<dim3(2048), B256, 0, stream>>>(tgt, bufT2, ln2g, ln2b, bufTg1);
  // 7. value projection (bf16 out) -- 128x256 tile, 8 waves, counted vmcnt (best measured)
  gemm_dma2_kernel<false,true><<<dim3(1360,1), B512, 0, stream>>>(src, wvalbf, b_val, bufVal, 174080, 256, 256);
  // 8. query2 = tgt1 + query_pos (into bufT2, free at this point)
  add_kernel<<<dim3(2048), B256, 0, stream>>>(bufTg1, qpos, bufT2, 524288);
  // 9. sampling offsets + attn-weight logits in ONE GEMM (N=384, bf16 weights)
  gemm_dma3_kernel<false,false><<<dim3(128,3), B256, 0, stream>>>(bufT2, woffawbf, bufBOA, bufOA, 8192, 384, 256);
  // 10. deformable sampling
  deform_kernel<<<dim3(2048), B256, 0, stream>>>(bufVal, bufOA, refp, bufO);
  // 11. output-context projection
  gemm_dma3_kernel<false,false><<<dim3(128,2), B256, 0, stream>>>(bufO, wocbf, b_oc, bufT2, 8192, 256, 256);
  // 12. tgt2 = LN1(tgt1 + ca)
  addln_kernel<<<dim3(2048), B256, 0, stream>>>(bufTg1, bufT2, ln1g, ln1b, bufTg2);
  // 13. FFN up + relu -- 128x256 tile
  gemm_dma2_kernel<true,false><<<dim3(64,4), B512, 0, stream>>>(bufTg2, w1bf, b1, bufH, 8192, 1024, 256);
  // 14. FFN down (K=1024)
  gemm_dma3_kernel<false,false><<<dim3(128,2), B256, 0, stream>>>(bufH, w2bf, b2, bufT2, 8192, 256, 1024);
  // 15. out = LN3(tgt2 + t2)
  addln_kernel<<<dim3(2048), B256, 0, stream>>>(bufTg2, bufT2, ln3g, ln3b, outF);
}